// Round 1
// baseline (393.177 us; speedup 1.0000x reference)
//
#include <hip/hip_runtime.h>
#include <cstdint>
#include <cstddef>

#define Bb 4
#define Nn 4096
#define Dd 1024
#define Hh 16
#define ROWS (Bb*Nn)   // 16384

typedef unsigned short u16;
typedef float    f32x4 __attribute__((ext_vector_type(4)));
typedef _Float16 f16x8 __attribute__((ext_vector_type(8)));
typedef u16      u16x2 __attribute__((ext_vector_type(2)));
typedef u16      u16x4 __attribute__((ext_vector_type(4)));
typedef u16      u16x8 __attribute__((ext_vector_type(8)));

__device__ inline u16 f2h(float f){ _Float16 h=(_Float16)f; return __builtin_bit_cast(u16,h); }
__device__ inline float h2f(u16 u){ return (float)__builtin_bit_cast(_Float16,u); }

__device__ inline void gl_lds16(const void* g, void* l){
  __builtin_amdgcn_global_load_lds(
      (const __attribute__((address_space(1))) void*)g,
      (__attribute__((address_space(3))) void*)l,
      16, 0, 0);
}

// ---------------- weight fp32 -> fp16 ----------------
__global__ __launch_bounds__(256) void wconv_k(const float* __restrict__ wq,
    const float* __restrict__ wk, const float* __restrict__ wv,
    const float* __restrict__ wo, u16* __restrict__ wbf)
{
  const int idx = blockIdx.x*256 + threadIdx.x;       // 1M threads, 4 floats each
  const int which = idx >> 18;                        // 2^18 float4 per 1024x1024 matrix
  const int rem = idx & ((1<<18)-1);
  const float* src = which==0?wq:which==1?wk:which==2?wv:wo;
  const f32x4 v = ((const f32x4*)src)[rem];
  u16x4 o;
  #pragma unroll
  for (int i=0;i<4;i++) o[i]=f2h(v[i]);
  ((u16x4*)(wbf + (size_t)which*(1u<<20)))[rem] = o;
}

// ---------------- log map: x -> x_tan (fp16) ----------------
__global__ __launch_bounds__(256) void logmap_k(const float* __restrict__ x,
    const float* __restrict__ curv, u16* __restrict__ xt)
{
  const int row = blockIdx.x, tid = threadIdx.x;
  const f32x4 v = ((const f32x4*)(x + (size_t)row*Dd))[tid];
  float ss = v[0]*v[0] + v[1]*v[1] + v[2]*v[2] + v[3]*v[3];
  #pragma unroll
  for (int o=32;o>0;o>>=1) ss += __shfl_down(ss, o, 64);
  __shared__ float red[4];
  if ((tid & 63) == 0) red[tid>>6] = ss;
  __syncthreads();
  const float sum = red[0]+red[1]+red[2]+red[3];
  const float c  = fmaxf(fabsf(curv[0]), 1e-6f);
  const float sc = sqrtf(fmaxf(c, 1e-6f));
  const float xn = fminf(fmaxf(sqrtf(sum), 1e-6f), 0.999f);
  const float a  = sc * xn;
  const float scale = atanhf(a) / (a + 1e-8f);
  u16x4 o;
  #pragma unroll
  for (int i=0;i<4;i++) o[i] = f2h(v[i]*scale);
  ((u16x4*)(xt + (size_t)row*Dd))[tid] = o;
}

// ---------------- exp map, in-place on d_out ----------------
__global__ __launch_bounds__(256) void expmap_k(float* __restrict__ out,
    const float* __restrict__ curv)
{
  const int row = blockIdx.x, tid = threadIdx.x;
  f32x4* p = (f32x4*)(out + (size_t)row*Dd);
  const f32x4 v = p[tid];
  float ss = v[0]*v[0]+v[1]*v[1]+v[2]*v[2]+v[3]*v[3];
  #pragma unroll
  for (int o=32;o>0;o>>=1) ss += __shfl_down(ss,o,64);
  __shared__ float red[4];
  if ((tid&63)==0) red[tid>>6]=ss;
  __syncthreads();
  const float sum = red[0]+red[1]+red[2]+red[3];
  const float c  = fmaxf(fabsf(curv[0]),1e-6f);
  const float sc = sqrtf(fmaxf(c,1e-6f));
  const float vn = fminf(fmaxf(sqrtf(sum),1e-6f),15.0f);
  const float a  = sc*vn;
  const float scale = tanhf(fminf(a,15.0f))/(a + 1e-8f);
  f32x4 o;
  #pragma unroll
  for (int i=0;i<4;i++) o[i]=v[i]*scale;
  p[tid]=o;
}

// ---------------- GEMM: out = A @ W^T + bias, fp16 MFMA ----------------
// mode 0: phi(q)->phiq  1: phi(k)->phik  2: v->vout  3: att@Wo^T+bo -> proj(fp32)
__global__ __launch_bounds__(256) void gemm_k(
    const u16* __restrict__ xt, const u16* __restrict__ att,
    const u16* __restrict__ wbf,
    const float* __restrict__ bq, const float* __restrict__ bk,
    const float* __restrict__ bv, const float* __restrict__ bo,
    u16* __restrict__ phiq, u16* __restrict__ phik, u16* __restrict__ vout,
    float* __restrict__ proj, int mode_base)
{
  const int mode = mode_base + blockIdx.z;
  const u16* A = (mode < 3) ? xt : att;
  const u16* W = wbf + (size_t)mode * (1u<<20);
  const float* bias = (mode==0)?bq:(mode==1)?bk:(mode==2)?bv:bo;
  u16* outh = (mode==0)?phiq:(mode==1)?phik:vout;

  __shared__ __align__(16) u16 As[128*64];
  __shared__ __align__(16) u16 Bs[128*64];

  const int tid = threadIdx.x;
  const int w = tid >> 6, lane = tid & 63;
  const int wr = w >> 1, wc = w & 1;
  const int bm0 = blockIdx.y * 128;
  const int bn0 = blockIdx.x * 128;

  f32x4 acc[4][4];
  #pragma unroll
  for (int i=0;i<4;i++)
    #pragma unroll
    for (int j=0;j<4;j++) acc[i][j] = (f32x4)(0.f);

  const int l8 = lane >> 3, l7 = lane & 7;

  for (int kt = 0; kt < Dd/64; ++kt){
    __syncthreads();
    #pragma unroll
    for (int i=0;i<4;i++){
      const int ci = w*4 + i;
      const int r  = ci*8 + l8;
      const int cch = l7 ^ (r & 7);           // pre-swizzled global source (rule #21)
      gl_lds16(A + (size_t)(bm0 + r)*Dd + kt*64 + cch*8, &As[ci*512]);
      gl_lds16(W + (size_t)(bn0 + r)*Dd + kt*64 + cch*8, &Bs[ci*512]);
    }
    __syncthreads();
    #pragma unroll
    for (int k2=0;k2<2;k2++){
      f16x8 af[4], bf[4];
      #pragma unroll
      for (int mi=0;mi<4;mi++){
        const int ar = wr*64 + mi*16 + (lane & 15);
        const int cb = (k2*64 + (lane>>4)*16) ^ ((ar & 7) << 4);  // swizzled read
        af[mi] = *(const f16x8*)((const char*)As + ar*128 + cb);
      }
      #pragma unroll
      for (int ni=0;ni<4;ni++){
        const int br = wc*64 + ni*16 + (lane & 15);
        const int cb = (k2*64 + (lane>>4)*16) ^ ((br & 7) << 4);
        bf[ni] = *(const f16x8*)((const char*)Bs + br*128 + cb);
      }
      #pragma unroll
      for (int mi=0;mi<4;mi++)
        #pragma unroll
        for (int ni=0;ni<4;ni++)
          acc[mi][ni] = __builtin_amdgcn_mfma_f32_16x16x32_f16(af[mi], bf[ni], acc[mi][ni], 0,0,0);
    }
  }

  // epilogue: D mapping col=lane&15, row=(lane>>4)*4+reg  [m89]
  #pragma unroll
  for (int ni=0;ni<4;ni++){
    const int col = bn0 + wc*64 + ni*16 + (lane & 15);
    const float bs = bias[col];
    #pragma unroll
    for (int mi=0;mi<4;mi++){
      const int row0 = bm0 + wr*64 + mi*16 + ((lane >> 4) << 2);
      #pragma unroll
      for (int r=0;r<4;r++){
        const float val = acc[mi][ni][r] + bs;
        const size_t off = (size_t)(row0 + r)*Dd + col;
        if (mode <= 1){
          const float p = val > 0.f ? val + 1.f : expf(val);  // phi = elu+1
          outh[off] = f2h(p);
        } else if (mode == 2){
          outh[off] = f2h(val);
        } else {
          proj[off] = val;
        }
      }
    }
  }
}

// ---------------- kv partials: kv[f][d] = sum_n phik[n,f]*v[n,d] ----------------
__global__ __launch_bounds__(256) void kvpart_k(const u16* __restrict__ phik,
    const u16* __restrict__ vbuf, float* __restrict__ pkv, float* __restrict__ pks)
{
  const int nc = blockIdx.x, bh = blockIdx.y;
  const int b = bh>>4, h = bh&15;
  const int tid = threadIdx.x;
  const int f0 = (tid&15)*4, d0 = (tid>>4)*4;
  __shared__ __align__(8) u16 ps[8][64];
  __shared__ __align__(8) u16 vs[8][64];
  float acc[4][4];
  float ks[4];
  #pragma unroll
  for (int i=0;i<4;i++){ ks[i]=0.f;
    #pragma unroll
    for (int j=0;j<4;j++) acc[i][j]=0.f; }
  const size_t base = ((size_t)b*Nn + nc*512)*Dd + h*64;
  const int rr = tid>>5, cc = (tid&31)*2;
  for (int it=0; it<64; ++it){
    __syncthreads();
    const size_t g = base + (size_t)(it*8 + rr)*Dd + cc;
    *(u16x2*)&ps[rr][cc] = *(const u16x2*)(phik + g);
    *(u16x2*)&vs[rr][cc] = *(const u16x2*)(vbuf + g);
    __syncthreads();
    #pragma unroll
    for (int nn=0;nn<8;nn++){
      float pk[4], vv[4];
      #pragma unroll
      for (int i=0;i<4;i++) pk[i]=h2f(ps[nn][f0+i]);
      #pragma unroll
      for (int j=0;j<4;j++) vv[j]=h2f(vs[nn][d0+j]);
      #pragma unroll
      for (int i=0;i<4;i++)
        #pragma unroll
        for (int j=0;j<4;j++) acc[i][j] += pk[i]*vv[j];
      if (tid < 16){
        #pragma unroll
        for (int i=0;i<4;i++) ks[i] += pk[i];
      }
    }
  }
  float* o = pkv + (size_t)(bh*8+nc)*4096;
  #pragma unroll
  for (int i=0;i<4;i++){
    f32x4 t;
    #pragma unroll
    for (int j=0;j<4;j++) t[j]=acc[i][j];
    *(f32x4*)&o[(f0+i)*64 + d0] = t;
  }
  if (tid < 16){
    float* os = pks + (size_t)(bh*8+nc)*64;
    #pragma unroll
    for (int i=0;i<4;i++) os[tid*4+i]=ks[i];
  }
}

// ---------------- reduce partials over 8 n-chunks ----------------
__global__ __launch_bounds__(256) void kvred_k(const float* __restrict__ pkv,
    const float* __restrict__ pks, float* __restrict__ kvf, float* __restrict__ ksf)
{
  const int bh = blockIdx.x, tid = threadIdx.x;
  #pragma unroll
  for (int i=0;i<4;i++){
    const int e = tid*16 + i*4;
    f32x4 s = (f32x4)(0.f);
    for (int p=0;p<8;p++)
      s += *(const f32x4*)&pkv[(size_t)(bh*8+p)*4096 + e];
    *(f32x4*)&kvf[(size_t)bh*4096 + e] = s;
  }
  if (tid < 64){
    float s=0.f;
    for (int p=0;p<8;p++) s += pks[(size_t)(bh*8+p)*64 + tid];
    ksf[bh*64+tid]=s;
  }
}

// ---------------- qkv + normalizer -> att (fp16) ----------------
__global__ __launch_bounds__(256) void attn_k(const u16* __restrict__ phiq,
    const float* __restrict__ kvf, const float* __restrict__ ksf, u16* __restrict__ att)
{
  const int bh = blockIdx.y, b = bh>>4, h = bh&15;
  const int n0 = blockIdx.x*64;
  const int tid = threadIdx.x;
  __shared__ __align__(16) float kvs[64*64];
  __shared__ float kss[64];
  __shared__ __align__(16) u16 pqs[64*64];
  const float* kvsrc = kvf + (size_t)bh*4096;
  #pragma unroll
  for (int i=0;i<4;i++){
    const int e = tid*4 + i*1024;
    *(f32x4*)&kvs[e] = *(const f32x4*)&kvsrc[e];
  }
  if (tid<64) kss[tid] = ksf[bh*64+tid];
  const size_t qbase = ((size_t)b*Nn + n0)*Dd + h*64;
  {
    const int rr = tid>>2, cc = (tid&3)*16;
    *(u16x8*)&pqs[rr*64+cc]   = *(const u16x8*)(phiq + qbase + (size_t)rr*Dd + cc);
    *(u16x8*)&pqs[rr*64+cc+8] = *(const u16x8*)(phiq + qbase + (size_t)rr*Dd + cc + 8);
  }
  __syncthreads();
  const int r = tid>>2, d0 = (tid&3)*16;
  float accd[16];
  #pragma unroll
  for (int j=0;j<16;j++) accd[j]=0.f;
  float nrm = 0.f;
  #pragma unroll 4
  for (int f=0; f<64; ++f){
    const float pq = h2f(pqs[r*64+f]);
    nrm += pq * kss[f];
    const float* kvrow = &kvs[f*64 + d0];
    #pragma unroll
    for (int j=0;j<16;j++) accd[j] += pq * kvrow[j];
  }
  const float inv = 1.f / fmaxf(nrm, 1e-6f);
  const size_t obase = ((size_t)b*Nn + n0 + r)*Dd + h*64 + d0;
  u16x8 o0, o1;
  #pragma unroll
  for (int j=0;j<8;j++){ o0[j]=f2h(accd[j]*inv); o1[j]=f2h(accd[8+j]*inv); }
  *(u16x8*)(att + obase)     = o0;
  *(u16x8*)(att + obase + 8) = o1;
}

extern "C" void kernel_launch(void* const* d_in, const int* in_sizes, int n_in,
                              void* d_out, int out_size, void* d_ws, size_t ws_size,
                              hipStream_t stream)
{
  const float* x  = (const float*)d_in[0];
  const float* cv = (const float*)d_in[1];
  const float* Wq = (const float*)d_in[2];
  const float* bq = (const float*)d_in[3];
  const float* Wk = (const float*)d_in[4];
  const float* bk = (const float*)d_in[5];
  const float* Wv = (const float*)d_in[6];
  const float* bv = (const float*)d_in[7];
  const float* Wo = (const float*)d_in[8];
  const float* bo = (const float*)d_in[9];
  float* out = (float*)d_out;
  char* ws = (char*)d_ws;
  const size_t MB = 1u<<20;
  if (ws_size < 136*MB) return;   // needs 136 MiB scratch

  u16* xt    = (u16*)(ws + 0);        // 32 MiB, dead after QKV gemm
  u16* wbf   = (u16*)(ws + 32*MB);    // 8 MiB (4 matrices fp16)
  u16* phiq  = (u16*)(ws + 40*MB);    // 32 MiB
  u16* phik  = (u16*)(ws + 72*MB);    // 32 MiB
  u16* vbuf  = (u16*)(ws + 104*MB);   // 32 MiB, dead after kvpart
  float* pkv = (float*)(ws + 0);      // 8 MiB   (reuses xt region)
  float* pks = (float*)(ws + 8*MB);   // 128 KiB
  float* kvf = (float*)(ws + 9*MB);   // 1 MiB
  float* ksf = (float*)(ws + 10*MB);  // 16 KiB
  u16* att   = (u16*)(ws + 104*MB);   // 32 MiB  (reuses vbuf region)

  wconv_k<<<4096, 256, 0, stream>>>(Wq, Wk, Wv, Wo, wbf);
  logmap_k<<<ROWS, 256, 0, stream>>>(x, cv, xt);
  gemm_k<<<dim3(8,128,3), 256, 0, stream>>>(xt, att, wbf, bq, bk, bv, bo,
                                            phiq, phik, vbuf, out, 0);
  kvpart_k<<<dim3(8,64), 256, 0, stream>>>(phik, vbuf, pkv, pks);
  kvred_k<<<64, 256, 0, stream>>>(pkv, pks, kvf, ksf);
  attn_k<<<dim3(64,64), 256, 0, stream>>>(phiq, kvf, ksf, att);
  gemm_k<<<dim3(8,128,1), 256, 0, stream>>>(xt, att, wbf, bq, bk, bv, bo,
                                            phiq, phik, vbuf, out, 3);
  expmap_k<<<ROWS, 256, 0, stream>>>(out, cv);
}

// Round 3
// 389.001 us; speedup vs baseline: 1.0107x; 1.0107x over previous
//
#include <hip/hip_runtime.h>
#include <cstdint>
#include <cstddef>

#define Bb 4
#define Nn 4096
#define Dd 1024
#define Hh 16
#define ROWS (Bb*Nn)   // 16384

typedef unsigned short u16;
typedef float    f32x4 __attribute__((ext_vector_type(4)));
typedef _Float16 f16x8 __attribute__((ext_vector_type(8)));
typedef u16      u16x4 __attribute__((ext_vector_type(4)));
typedef u16      u16x8 __attribute__((ext_vector_type(8)));

__device__ inline u16 f2h(float f){ _Float16 h=(_Float16)f; return __builtin_bit_cast(u16,h); }
__device__ inline float h2f(u16 u){ return (float)__builtin_bit_cast(_Float16,u); }

__device__ inline void gl_lds16(const void* g, void* l){
  __builtin_amdgcn_global_load_lds(
      (const __attribute__((address_space(1))) void*)g,
      (__attribute__((address_space(3))) void*)l,
      16, 0, 0);
}

// ------- weights fp32->fp16, plus q/k/v bias concat -------
__global__ __launch_bounds__(256) void wconv_k(const float* __restrict__ wq,
    const float* __restrict__ wk, const float* __restrict__ wv,
    const float* __restrict__ wo,
    const float* __restrict__ bq, const float* __restrict__ bk,
    const float* __restrict__ bv,
    u16* __restrict__ wbf, float* __restrict__ bcat)
{
  const int idx = blockIdx.x*256 + threadIdx.x;
  if (idx < (1<<20)){
    const int which = idx >> 18;
    const int rem = idx & ((1<<18)-1);
    const float* src = which==0?wq:which==1?wk:which==2?wv:wo;
    const f32x4 v = ((const f32x4*)src)[rem];
    u16x4 o;
    #pragma unroll
    for (int i=0;i<4;i++) o[i]=f2h(v[i]);
    ((u16x4*)(wbf + (size_t)which*(1u<<20)))[rem] = o;
  } else {
    const int t = idx - (1<<20);
    if (t < 3072)
      bcat[t] = (t<1024) ? bq[t] : (t<2048) ? bk[t-1024] : bv[t-2048];
  }
}

// ------- log map: x -> x_tan (fp16) -------
__global__ __launch_bounds__(256) void logmap_k(const float* __restrict__ x,
    const float* __restrict__ curv, u16* __restrict__ xt)
{
  const int row = blockIdx.x, tid = threadIdx.x;
  const f32x4 v = ((const f32x4*)(x + (size_t)row*Dd))[tid];
  float ss = v[0]*v[0] + v[1]*v[1] + v[2]*v[2] + v[3]*v[3];
  #pragma unroll
  for (int o=32;o>0;o>>=1) ss += __shfl_down(ss, o, 64);
  __shared__ float red[4];
  if ((tid & 63) == 0) red[tid>>6] = ss;
  __syncthreads();
  const float sum = red[0]+red[1]+red[2]+red[3];
  const float c  = fmaxf(fabsf(curv[0]), 1e-6f);
  const float sc = sqrtf(fmaxf(c, 1e-6f));
  const float xn = fminf(fmaxf(sqrtf(sum), 1e-6f), 0.999f);
  const float a  = sc * xn;
  const float scale = atanhf(a) / (a + 1e-8f);
  u16x4 o;
  #pragma unroll
  for (int i=0;i<4;i++) o[i] = f2h(v[i]*scale);
  ((u16x4*)(xt + (size_t)row*Dd))[tid] = o;
}

// ------- exp map: proj (fp16) -> out (fp32) -------
__global__ __launch_bounds__(256) void expmap_k(const u16* __restrict__ proj,
    const float* __restrict__ curv, float* __restrict__ out)
{
  const int row = blockIdx.x, tid = threadIdx.x;
  const u16x4 hv = ((const u16x4*)(proj + (size_t)row*Dd))[tid];
  float v[4];
  #pragma unroll
  for (int i=0;i<4;i++) v[i]=h2f(hv[i]);
  float ss = v[0]*v[0]+v[1]*v[1]+v[2]*v[2]+v[3]*v[3];
  #pragma unroll
  for (int o=32;o>0;o>>=1) ss += __shfl_down(ss,o,64);
  __shared__ float red[4];
  if ((tid&63)==0) red[tid>>6]=ss;
  __syncthreads();
  const float sum = red[0]+red[1]+red[2]+red[3];
  const float c  = fmaxf(fabsf(curv[0]),1e-6f);
  const float sc = sqrtf(fmaxf(c,1e-6f));
  const float vn = fminf(fmaxf(sqrtf(sum),1e-6f),15.0f);
  const float a  = sc*vn;
  const float scale = tanhf(fminf(a,15.0f))/(a + 1e-8f);
  f32x4 o;
  #pragma unroll
  for (int i=0;i<4;i++) o[i]=v[i]*scale;
  ((f32x4*)(out + (size_t)row*Dd))[tid]=o;
}

// ------- GEMM: out = A @ W^T + bias (fp16 MFMA), optional phi=elu+1 -------
__global__ __launch_bounds__(256) void gemm_k(
    const u16* __restrict__ A, const u16* __restrict__ W,
    const float* __restrict__ bias,
    u16* __restrict__ outb, size_t mode_stride, int nbn, int phi_modes)
{
  __shared__ __align__(16) char smem[32768];
  u16* As = (u16*)smem;
  u16* Bs = (u16*)(smem + 16384);

  const int nwg = gridDim.x;
  const int bid = blockIdx.x;
  const int wgid = (bid & 7)*(nwg >> 3) + (bid >> 3);   // XCD-chunked (nwg%8==0)
  const int bm = wgid / nbn, bn = wgid % nbn;           // bm-major: A-tile reuse in L2
  const int bm0 = bm*128, bn0 = bn*128;

  const int tid = threadIdx.x;
  const int w = tid >> 6, lane = tid & 63;
  const int wr = w >> 1, wc = w & 1;

  f32x4 acc[4][4];
  #pragma unroll
  for (int i=0;i<4;i++)
    #pragma unroll
    for (int j=0;j<4;j++) acc[i][j] = (f32x4)(0.f);

  const int l8 = lane >> 3, l7 = lane & 7;

  for (int kt = 0; kt < Dd/64; ++kt){
    __syncthreads();
    #pragma unroll
    for (int i=0;i<4;i++){
      const int ci = w*4 + i;
      const int r  = ci*8 + l8;
      const int cch = l7 ^ (r & 7);           // pre-swizzled global source (rule #21)
      gl_lds16(A + (size_t)(bm0 + r)*Dd + kt*64 + cch*8, &As[ci*512]);
      gl_lds16(W + (size_t)(bn0 + r)*Dd + kt*64 + cch*8, &Bs[ci*512]);
    }
    __syncthreads();
    #pragma unroll
    for (int k2=0;k2<2;k2++){
      f16x8 af[4], bf[4];
      #pragma unroll
      for (int mi=0;mi<4;mi++){
        const int ar = wr*64 + mi*16 + (lane & 15);
        const int cb = (k2*64 + (lane>>4)*16) ^ ((ar & 7) << 4);  // swizzled read
        af[mi] = *(const f16x8*)((const char*)As + ar*128 + cb);
      }
      #pragma unroll
      for (int ni=0;ni<4;ni++){
        const int br = wc*64 + ni*16 + (lane & 15);
        const int cb = (k2*64 + (lane>>4)*16) ^ ((br & 7) << 4);
        bf[ni] = *(const f16x8*)((const char*)Bs + br*128 + cb);
      }
      #pragma unroll
      for (int mi=0;mi<4;mi++)
        #pragma unroll
        for (int ni=0;ni<4;ni++)
          acc[mi][ni] = __builtin_amdgcn_mfma_f32_16x16x32_f16(af[mi], bf[ni], acc[mi][ni], 0,0,0);
    }
  }

  // ---- epilogue: bias+phi in-register, LDS transpose, coalesced u16x8 stores ----
  __syncthreads();
  u16* Ts = (u16*)smem;                        // [128][128] fp16, XOR-swizzled
  const int dophi = (bn0 >> 10) < phi_modes;   // block-uniform
  #pragma unroll
  for (int ni=0;ni<4;ni++){
    const int col = wc*64 + ni*16 + (lane & 15);
    const float bs = bias[bn0 + col];
    #pragma unroll
    for (int mi=0;mi<4;mi++){
      const int row0 = wr*64 + mi*16 + ((lane>>4)<<2);
      #pragma unroll
      for (int r=0;r<4;r++){
        float val = acc[mi][ni][r] + bs;
        if (dophi) val = val > 0.f ? val + 1.f : __expf(val);
        const int row = row0 + r;
        const int bo_ = (row*256 + col*2) ^ ((row&7)<<4);
        *(u16*)((char*)Ts + bo_) = f2h(val);
      }
    }
  }
  __syncthreads();
  {
    const int r = tid >> 1, ch = (tid & 1)*64;
    u16* ob = outb + (size_t)(bn0 >> 10) * mode_stride
                   + (size_t)(bm0 + r)*Dd + (bn0 & 1023) + ch;
    #pragma unroll
    for (int j=0;j<8;j++){
      const int bo_ = (r*256 + (ch + j*8)*2) ^ ((r&7)<<4);
      *(u16x8*)(ob + j*8) = *(const u16x8*)((const char*)Ts + bo_);
    }
  }
}

// ------- kv partials: kv[f][d] = sum_n phik[n,f]*v[n,d] -------
__global__ __launch_bounds__(256) void kvpart_k(const u16* __restrict__ phik,
    const u16* __restrict__ vbuf, float* __restrict__ pkv, float* __restrict__ pks)
{
  const int nc = blockIdx.x, bh = blockIdx.y;
  const int b = bh>>4, h = bh&15;
  const int tid = threadIdx.x;
  const int f0 = (tid&15)*4, d0 = (tid>>4)*4;
  __shared__ __align__(16) u16 ps[16*64];
  __shared__ __align__(16) u16 vs[16*64];
  float acc[4][4];
  float ks[4];
  #pragma unroll
  for (int i=0;i<4;i++){ ks[i]=0.f;
    #pragma unroll
    for (int j=0;j<4;j++) acc[i][j]=0.f; }
  const size_t base = ((size_t)b*Nn + nc*512)*Dd + h*64;
  const int half = tid>>7, rr = (tid&127)>>3, cc = (tid&7)*8;
  const u16* src = half ? vbuf : phik;
  u16* dst = half ? vs : ps;
  const int wb = rr*128 + ((cc*2) ^ ((rr&7)<<4));   // swizzled LDS write (byte off = cc*2)
  for (int it=0; it<32; ++it){
    __syncthreads();
    *(u16x8*)((char*)dst + wb) = *(const u16x8*)(src + base + (size_t)(it*16+rr)*Dd + cc);
    __syncthreads();
    #pragma unroll 4
    for (int nn=0;nn<16;nn++){
      const u16* pf = (const u16*)((const char*)ps + nn*128 + ((f0*2) ^ ((nn&7)<<4)));
      const u16* vf = (const u16*)((const char*)vs + nn*128 + ((d0*2) ^ ((nn&7)<<4)));
      float pk[4], vv[4];
      #pragma unroll
      for (int i=0;i<4;i++) pk[i]=h2f(pf[i]);
      #pragma unroll
      for (int j=0;j<4;j++) vv[j]=h2f(vf[j]);
      #pragma unroll
      for (int i=0;i<4;i++)
        #pragma unroll
        for (int j=0;j<4;j++) acc[i][j] += pk[i]*vv[j];
      if (tid < 16){
        #pragma unroll
        for (int i=0;i<4;i++) ks[i] += pk[i];
      }
    }
  }
  float* o = pkv + (size_t)(bh*8+nc)*4096;
  #pragma unroll
  for (int i=0;i<4;i++){
    f32x4 t;
    #pragma unroll
    for (int j=0;j<4;j++) t[j]=acc[i][j];
    *(f32x4*)&o[(f0+i)*64 + d0] = t;
  }
  if (tid < 16){
    float* os = pks + (size_t)(bh*8+nc)*64;
    #pragma unroll
    for (int i=0;i<4;i++) os[tid*4+i]=ks[i];
  }
}

// ------- reduce partials over 8 n-chunks -------
__global__ __launch_bounds__(256) void kvred_k(const float* __restrict__ pkv,
    const float* __restrict__ pks, float* __restrict__ kvf, float* __restrict__ ksf)
{
  const int bh = blockIdx.x, tid = threadIdx.x;
  #pragma unroll
  for (int i=0;i<4;i++){
    const int e = tid*16 + i*4;
    f32x4 s = (f32x4)(0.f);
    for (int p=0;p<8;p++)
      s += *(const f32x4*)&pkv[(size_t)(bh*8+p)*4096 + e];
    *(f32x4*)&kvf[(size_t)bh*4096 + e] = s;
  }
  if (tid < 64){
    float s=0.f;
    for (int p=0;p<8;p++) s += pks[(size_t)(bh*8+p)*64 + tid];
    ksf[bh*64+tid]=s;
  }
}

// ------- qkv + normalizer -> att (fp16) -------
__global__ __launch_bounds__(256) void attn_k(const u16* __restrict__ phiq,
    const float* __restrict__ kvf, const float* __restrict__ ksf, u16* __restrict__ att)
{
  const int bh = blockIdx.y, b = bh>>4, h = bh&15;
  const int n0 = blockIdx.x*64;
  const int tid = threadIdx.x;
  __shared__ __align__(16) float kvs[64*64];
  __shared__ float kss[64];
  __shared__ __align__(16) u16 pqs[64*64];
  const float* kvsrc = kvf + (size_t)bh*4096;
  #pragma unroll
  for (int i=0;i<4;i++){
    const int e = tid*4 + i*1024;
    *(f32x4*)&kvs[e] = *(const f32x4*)&kvsrc[e];
  }
  if (tid<64) kss[tid] = ksf[bh*64+tid];
  const size_t qbase = ((size_t)b*Nn + n0)*Dd + h*64;
  {
    const int rr = tid>>2, cc = (tid&3)*16;
    *(u16x8*)&pqs[rr*64+cc]   = *(const u16x8*)(phiq + qbase + (size_t)rr*Dd + cc);
    *(u16x8*)&pqs[rr*64+cc+8] = *(const u16x8*)(phiq + qbase + (size_t)rr*Dd + cc + 8);
  }
  __syncthreads();
  const int r = tid>>2, d0 = (tid&3)*16;
  float accd[16];
  #pragma unroll
  for (int j=0;j<16;j++) accd[j]=0.f;
  float nrm = 0.f;
  #pragma unroll 4
  for (int f=0; f<64; ++f){
    const float pq = h2f(pqs[r*64+f]);
    nrm += pq * kss[f];
    const float* kvrow = &kvs[f*64 + d0];
    #pragma unroll
    for (int j=0;j<16;j++) accd[j] += pq * kvrow[j];
  }
  const float inv = 1.f / fmaxf(nrm, 1e-6f);
  const size_t obase = ((size_t)b*Nn + n0 + r)*Dd + h*64 + d0;
  u16x8 o0, o1;
  #pragma unroll
  for (int j=0;j<8;j++){ o0[j]=f2h(accd[j]*inv); o1[j]=f2h(accd[8+j]*inv); }
  *(u16x8*)(att + obase)     = o0;
  *(u16x8*)(att + obase + 8) = o1;
}

extern "C" void kernel_launch(void* const* d_in, const int* in_sizes, int n_in,
                              void* d_out, int out_size, void* d_ws, size_t ws_size,
                              hipStream_t stream)
{
  const float* x  = (const float*)d_in[0];
  const float* cv = (const float*)d_in[1];
  const float* Wq = (const float*)d_in[2];
  const float* bq = (const float*)d_in[3];
  const float* Wk = (const float*)d_in[4];
  const float* bk = (const float*)d_in[5];
  const float* Wv = (const float*)d_in[6];
  const float* bv = (const float*)d_in[7];
  const float* Wo = (const float*)d_in[8];
  const float* bo = (const float*)d_in[9];
  float* out = (float*)d_out;
  char* ws = (char*)d_ws;
  const size_t MB = 1u<<20;
  if (ws_size < 136*MB) return;

  u16* xt     = (u16*)(ws + 0);        // 32 MiB, dead after QKV gemm
  u16* wbf    = (u16*)(ws + 32*MB);    // 8 MiB (Wq|Wk|Wv|Wo fp16)
  u16* phiq   = (u16*)(ws + 40*MB);    // 32 MiB (phiq|phik|vbuf contiguous)
  u16* phik   = (u16*)(ws + 72*MB);
  u16* vbuf   = (u16*)(ws + 104*MB);
  float* pkv  = (float*)(ws + 0);      // reuses xt region after QKV gemm
  float* pks  = (float*)(ws + 8*MB);
  float* kvf  = (float*)(ws + 9*MB);
  float* ksf  = (float*)(ws + 10*MB);
  u16* att    = (u16*)(ws + 104*MB);   // reuses vbuf after kvpart
  u16* proj16 = (u16*)(ws + 40*MB);    // reuses phiq after attn
  float* bcat = out + ((size_t)out_size - 4096);  // d_out tail, dead before expmap

  wconv_k<<<4108, 256, 0, stream>>>(Wq, Wk, Wv, Wo, bq, bk, bv, wbf, bcat);
  logmap_k<<<ROWS, 256, 0, stream>>>(x, cv, xt);
  gemm_k<<<3072, 256, 0, stream>>>(xt, wbf, bcat, phiq,
                                   (size_t)ROWS*Dd, 24, 2);      // fused QKV
  kvpart_k<<<dim3(8,64), 256, 0, stream>>>(phik, vbuf, pkv, pks);
  kvred_k<<<64, 256, 0, stream>>>(pkv, pks, kvf, ksf);
  attn_k<<<dim3(64,64), 256, 0, stream>>>(phiq, kvf, ksf, att);
  gemm_k<<<1024, 256, 0, stream>>>(att, wbf + (size_t)3*(1u<<20), bo, proj16,
                                   0, 8, 0);                     // out-proj
  expmap_k<<<ROWS, 256, 0, stream>>>(proj16, cv, out);
}

// Round 4
// 328.814 us; speedup vs baseline: 1.1957x; 1.1830x over previous
//
#include <hip/hip_runtime.h>
#include <cstdint>
#include <cstddef>

#define Bb 4
#define Nn 4096
#define Dd 1024
#define Hh 16
#define ROWS (Bb*Nn)   // 16384

typedef unsigned short u16;
typedef float    f32x4 __attribute__((ext_vector_type(4)));
typedef _Float16 f16x8 __attribute__((ext_vector_type(8)));
typedef u16      u16x4 __attribute__((ext_vector_type(4)));
typedef u16      u16x8 __attribute__((ext_vector_type(8)));

__device__ inline u16 f2h(float f){ _Float16 h=(_Float16)f; return __builtin_bit_cast(u16,h); }
__device__ inline float h2f(u16 u){ return (float)__builtin_bit_cast(_Float16,u); }

__device__ inline void gl_lds16(const void* g, void* l){
  __builtin_amdgcn_global_load_lds(
      (const __attribute__((address_space(1))) void*)g,
      (__attribute__((address_space(3))) void*)l,
      16, 0, 0);
}

// ------- weights fp32->fp16, plus q/k/v bias concat -------
__global__ __launch_bounds__(256) void wconv_k(const float* __restrict__ wq,
    const float* __restrict__ wk, const float* __restrict__ wv,
    const float* __restrict__ wo,
    const float* __restrict__ bq, const float* __restrict__ bk,
    const float* __restrict__ bv,
    u16* __restrict__ wbf, float* __restrict__ bcat)
{
  const int idx = blockIdx.x*256 + threadIdx.x;
  if (idx < (1<<20)){
    const int which = idx >> 18;
    const int rem = idx & ((1<<18)-1);
    const float* src = which==0?wq:which==1?wk:which==2?wv:wo;
    const f32x4 v = ((const f32x4*)src)[rem];
    u16x4 o;
    #pragma unroll
    for (int i=0;i<4;i++) o[i]=f2h(v[i]);
    ((u16x4*)(wbf + (size_t)which*(1u<<20)))[rem] = o;
  } else {
    const int t = idx - (1<<20);
    if (t < 3072)
      bcat[t] = (t<1024) ? bq[t] : (t<2048) ? bk[t-1024] : bv[t-2048];
  }
}

// ------- log map: x -> x_tan (fp16) -------
__global__ __launch_bounds__(256) void logmap_k(const float* __restrict__ x,
    const float* __restrict__ curv, u16* __restrict__ xt)
{
  const int row = blockIdx.x, tid = threadIdx.x;
  const f32x4 v = ((const f32x4*)(x + (size_t)row*Dd))[tid];
  float ss = v[0]*v[0] + v[1]*v[1] + v[2]*v[2] + v[3]*v[3];
  #pragma unroll
  for (int o=32;o>0;o>>=1) ss += __shfl_down(ss, o, 64);
  __shared__ float red[4];
  if ((tid & 63) == 0) red[tid>>6] = ss;
  __syncthreads();
  const float sum = red[0]+red[1]+red[2]+red[3];
  const float c  = fmaxf(fabsf(curv[0]), 1e-6f);
  const float sc = sqrtf(fmaxf(c, 1e-6f));
  const float xn = fminf(fmaxf(sqrtf(sum), 1e-6f), 0.999f);
  const float a  = sc * xn;
  const float scale = atanhf(a) / (a + 1e-8f);
  u16x4 o;
  #pragma unroll
  for (int i=0;i<4;i++) o[i] = f2h(v[i]*scale);
  ((u16x4*)(xt + (size_t)row*Dd))[tid] = o;
}

// ------- exp map: proj (fp16) -> out (fp32) -------
__global__ __launch_bounds__(256) void expmap_k(const u16* __restrict__ proj,
    const float* __restrict__ curv, float* __restrict__ out)
{
  const int row = blockIdx.x, tid = threadIdx.x;
  const u16x4 hv = ((const u16x4*)(proj + (size_t)row*Dd))[tid];
  float v[4];
  #pragma unroll
  for (int i=0;i<4;i++) v[i]=h2f(hv[i]);
  float ss = v[0]*v[0]+v[1]*v[1]+v[2]*v[2]+v[3]*v[3];
  #pragma unroll
  for (int o=32;o>0;o>>=1) ss += __shfl_down(ss,o,64);
  __shared__ float red[4];
  if ((tid&63)==0) red[tid>>6]=ss;
  __syncthreads();
  const float sum = red[0]+red[1]+red[2]+red[3];
  const float c  = fmaxf(fabsf(curv[0]),1e-6f);
  const float sc = sqrtf(fmaxf(c,1e-6f));
  const float vn = fminf(fmaxf(sqrtf(sum),1e-6f),15.0f);
  const float a  = sc*vn;
  const float scale = tanhf(fminf(a,15.0f))/(a + 1e-8f);
  f32x4 o;
  #pragma unroll
  for (int i=0;i<4;i++) o[i]=v[i]*scale;
  ((f32x4*)(out + (size_t)row*Dd))[tid]=o;
}

// ------- 256x256-tile GEMM: out = A @ W^T + bias (fp16 MFMA), opt phi -------
// 8 waves (2Mx4N), BK=64, double-buffered LDS (2x64KB), prefetch-issue-first.
__global__ __launch_bounds__(512, 1) void gemm8_k(
    const u16* __restrict__ A, const u16* __restrict__ W,
    const float* __restrict__ bias,
    u16* __restrict__ outb, size_t mode_stride, int nbn, int phi_modes)
{
  __shared__ __align__(16) char smem[131072];

  const int nwg = gridDim.x;
  const int bid = blockIdx.x;
  const int wgid = (bid & 7)*(nwg >> 3) + (bid >> 3);   // XCD-chunked (nwg%8==0)
  const int bm = wgid / nbn, bn = wgid % nbn;           // bm-major: A-tile L2 reuse
  const int bm0 = bm*256, bn0 = bn*256;

  const int tid = threadIdx.x;
  const int w = tid >> 6, lane = tid & 63;
  const int wr = w >> 2, wc = w & 3;                    // 2M x 4N wave grid
  const int l8 = lane >> 3, l7 = lane & 7;

  f32x4 acc[8][4];
  #pragma unroll
  for (int i=0;i<8;i++)
    #pragma unroll
    for (int j=0;j<4;j++) acc[i][j] = (f32x4)(0.f);

  // stage K-tile kt into buffer d (A: 256x64, B: 256x64, linear LDS,
  // pre-swizzled global source per rule #21)
  auto STAGE = [&](int d, int kt){
    char* Ab = smem + d*65536;
    char* Bbp = smem + d*65536 + 32768;
    #pragma unroll
    for (int i=0;i<4;i++){
      const int r = w*32 + i*8 + l8;
      const int cch = l7 ^ (r & 7);
      gl_lds16(A + (size_t)(bm0 + r)*Dd + kt*64 + cch*8, Ab + (w*32+i*8)*128);
      gl_lds16(W + (size_t)(bn0 + r)*Dd + kt*64 + cch*8, Bbp + (w*32+i*8)*128);
    }
  };

  auto COMPUTE = [&](int d){
    const char* Ab = smem + d*65536;
    const char* Bbp = smem + d*65536 + 32768;
    #pragma unroll
    for (int ks=0; ks<2; ks++){
      f16x8 bf[4];
      #pragma unroll
      for (int ni=0; ni<4; ni++){
        const int br = wc*64 + ni*16 + (lane & 15);
        const int cb = (ks*64 + (lane>>4)*16) ^ ((br & 7) << 4);   // T2 swizzle
        bf[ni] = *(const f16x8*)(Bbp + br*128 + cb);
      }
      __builtin_amdgcn_s_setprio(1);
      #pragma unroll
      for (int mi=0; mi<8; mi++){
        const int ar = wr*128 + mi*16 + (lane & 15);
        const int cb = (ks*64 + (lane>>4)*16) ^ ((ar & 7) << 4);
        const f16x8 af = *(const f16x8*)(Ab + ar*128 + cb);
        #pragma unroll
        for (int ni=0; ni<4; ni++)
          acc[mi][ni] = __builtin_amdgcn_mfma_f32_16x16x32_f16(af, bf[ni], acc[mi][ni], 0,0,0);
      }
      __builtin_amdgcn_s_setprio(0);
    }
  };

  STAGE(0, 0);
  __syncthreads();
  int d = 0;
  for (int kt = 0; kt < Dd/64; ++kt){
    if (kt < Dd/64 - 1) STAGE(d^1, kt+1);   // issue-first: latency hides under MFMA
    COMPUTE(d);
    __syncthreads();                         // single drain per K-tile, post-compute
    d ^= 1;
  }

  // ---- epilogue: bias+phi in-register, LDS transpose (256x256 fp16), coalesced stores
  u16* Ts = (u16*)smem;
  const int dophi = (bn0 >> 10) < phi_modes;
  #pragma unroll
  for (int ni=0;ni<4;ni++){
    const int col = wc*64 + ni*16 + (lane & 15);
    const float bs = bias[bn0 + col];
    #pragma unroll
    for (int mi=0;mi<8;mi++){
      const int row0 = wr*128 + mi*16 + ((lane>>4)<<2);
      #pragma unroll
      for (int r=0;r<4;r++){
        float val = acc[mi][ni][r] + bs;
        if (dophi) val = val > 0.f ? val + 1.f : __expf(val);
        const int row = row0 + r;
        const int bo_ = (row*512 + col*2) ^ ((row&7)<<4);
        *(u16*)((char*)Ts + bo_) = f2h(val);
      }
    }
  }
  __syncthreads();
  {
    #pragma unroll
    for (int j=0;j<16;j++){
      const int row = j*16 + w*2 + (lane>>5);
      const int cb2 = (lane&31)*16;
      const int bo_ = (row*512 + cb2) ^ ((row&7)<<4);
      u16* ob = outb + (size_t)(bn0 >> 10) * mode_stride
                     + (size_t)(bm0 + row)*Dd + (bn0 & 1023) + (cb2>>1);
      *(u16x8*)ob = *(const u16x8*)((const char*)Ts + bo_);
    }
  }
}

// ------- kv partials: kv[f][d] = sum_n phik[n,f]*v[n,d] -------
__global__ __launch_bounds__(256) void kvpart_k(const u16* __restrict__ phik,
    const u16* __restrict__ vbuf, float* __restrict__ pkv, float* __restrict__ pks)
{
  const int nc = blockIdx.x, bh = blockIdx.y;
  const int b = bh>>4, h = bh&15;
  const int tid = threadIdx.x;
  const int f0 = (tid&15)*4, d0 = (tid>>4)*4;
  __shared__ __align__(16) u16 ps[16*64];
  __shared__ __align__(16) u16 vs[16*64];
  float acc[4][4];
  float ks[4];
  #pragma unroll
  for (int i=0;i<4;i++){ ks[i]=0.f;
    #pragma unroll
    for (int j=0;j<4;j++) acc[i][j]=0.f; }
  const size_t base = ((size_t)b*Nn + nc*512)*Dd + h*64;
  const int half = tid>>7, rr = (tid&127)>>3, cc = (tid&7)*8;
  const u16* src = half ? vbuf : phik;
  u16* dst = half ? vs : ps;
  const int wb = rr*128 + ((cc*2) ^ ((rr&7)<<4));   // swizzled LDS write (byte off = cc*2)
  for (int it=0; it<32; ++it){
    __syncthreads();
    *(u16x8*)((char*)dst + wb) = *(const u16x8*)(src + base + (size_t)(it*16+rr)*Dd + cc);
    __syncthreads();
    #pragma unroll 4
    for (int nn=0;nn<16;nn++){
      const u16* pf = (const u16*)((const char*)ps + nn*128 + ((f0*2) ^ ((nn&7)<<4)));
      const u16* vf = (const u16*)((const char*)vs + nn*128 + ((d0*2) ^ ((nn&7)<<4)));
      float pk[4], vv[4];
      #pragma unroll
      for (int i=0;i<4;i++) pk[i]=h2f(pf[i]);
      #pragma unroll
      for (int j=0;j<4;j++) vv[j]=h2f(vf[j]);
      #pragma unroll
      for (int i=0;i<4;i++)
        #pragma unroll
        for (int j=0;j<4;j++) acc[i][j] += pk[i]*vv[j];
      if (tid < 16){
        #pragma unroll
        for (int i=0;i<4;i++) ks[i] += pk[i];
      }
    }
  }
  float* o = pkv + (size_t)(bh*8+nc)*4096;
  #pragma unroll
  for (int i=0;i<4;i++){
    f32x4 t;
    #pragma unroll
    for (int j=0;j<4;j++) t[j]=acc[i][j];
    *(f32x4*)&o[(f0+i)*64 + d0] = t;
  }
  if (tid < 16){
    float* os = pks + (size_t)(bh*8+nc)*64;
    #pragma unroll
    for (int i=0;i<4;i++) os[tid*4+i]=ks[i];
  }
}

// ------- reduce partials over 8 n-chunks -------
__global__ __launch_bounds__(256) void kvred_k(const float* __restrict__ pkv,
    const float* __restrict__ pks, float* __restrict__ kvf, float* __restrict__ ksf)
{
  const int bh = blockIdx.x, tid = threadIdx.x;
  #pragma unroll
  for (int i=0;i<4;i++){
    const int e = tid*16 + i*4;
    f32x4 s = (f32x4)(0.f);
    for (int p=0;p<8;p++)
      s += *(const f32x4*)&pkv[(size_t)(bh*8+p)*4096 + e];
    *(f32x4*)&kvf[(size_t)bh*4096 + e] = s;
  }
  if (tid < 64){
    float s=0.f;
    for (int p=0;p<8;p++) s += pks[(size_t)(bh*8+p)*64 + tid];
    ksf[bh*64+tid]=s;
  }
}

// ------- qkv + normalizer -> att (fp16) -------
__global__ __launch_bounds__(256) void attn_k(const u16* __restrict__ phiq,
    const float* __restrict__ kvf, const float* __restrict__ ksf, u16* __restrict__ att)
{
  const int bh = blockIdx.y, b = bh>>4, h = bh&15;
  const int n0 = blockIdx.x*64;
  const int tid = threadIdx.x;
  __shared__ __align__(16) float kvs[64*64];
  __shared__ float kss[64];
  __shared__ __align__(16) u16 pqs[64*64];
  const float* kvsrc = kvf + (size_t)bh*4096;
  #pragma unroll
  for (int i=0;i<4;i++){
    const int e = tid*4 + i*1024;
    *(f32x4*)&kvs[e] = *(const f32x4*)&kvsrc[e];
  }
  if (tid<64) kss[tid] = ksf[bh*64+tid];
  const size_t qbase = ((size_t)b*Nn + n0)*Dd + h*64;
  {
    const int rr = tid>>2, cc = (tid&3)*16;
    *(u16x8*)&pqs[rr*64+cc]   = *(const u16x8*)(phiq + qbase + (size_t)rr*Dd + cc);
    *(u16x8*)&pqs[rr*64+cc+8] = *(const u16x8*)(phiq + qbase + (size_t)rr*Dd + cc + 8);
  }
  __syncthreads();
  const int r = tid>>2, d0 = (tid&3)*16;
  float accd[16];
  #pragma unroll
  for (int j=0;j<16;j++) accd[j]=0.f;
  float nrm = 0.f;
  #pragma unroll 4
  for (int f=0; f<64; ++f){
    const float pq = h2f(pqs[r*64+f]);
    nrm += pq * kss[f];
    const float* kvrow = &kvs[f*64 + d0];
    #pragma unroll
    for (int j=0;j<16;j++) accd[j] += pq * kvrow[j];
  }
  const float inv = 1.f / fmaxf(nrm, 1e-6f);
  const size_t obase = ((size_t)b*Nn + n0 + r)*Dd + h*64 + d0;
  u16x8 o0, o1;
  #pragma unroll
  for (int j=0;j<8;j++){ o0[j]=f2h(accd[j]*inv); o1[j]=f2h(accd[8+j]*inv); }
  *(u16x8*)(att + obase)     = o0;
  *(u16x8*)(att + obase + 8) = o1;
}

extern "C" void kernel_launch(void* const* d_in, const int* in_sizes, int n_in,
                              void* d_out, int out_size, void* d_ws, size_t ws_size,
                              hipStream_t stream)
{
  const float* x  = (const float*)d_in[0];
  const float* cv = (const float*)d_in[1];
  const float* Wq = (const float*)d_in[2];
  const float* bq = (const float*)d_in[3];
  const float* Wk = (const float*)d_in[4];
  const float* bk = (const float*)d_in[5];
  const float* Wv = (const float*)d_in[6];
  const float* bv = (const float*)d_in[7];
  const float* Wo = (const float*)d_in[8];
  const float* bo = (const float*)d_in[9];
  float* out = (float*)d_out;
  char* ws = (char*)d_ws;
  const size_t MB = 1u<<20;
  if (ws_size < 136*MB) return;

  u16* xt     = (u16*)(ws + 0);        // 32 MiB, dead after QKV gemm
  u16* wbf    = (u16*)(ws + 32*MB);    // 8 MiB (Wq|Wk|Wv|Wo fp16)
  u16* phiq   = (u16*)(ws + 40*MB);    // 32 MiB (phiq|phik|vbuf contiguous)
  u16* phik   = (u16*)(ws + 72*MB);
  u16* vbuf   = (u16*)(ws + 104*MB);
  float* pkv  = (float*)(ws + 0);      // reuses xt region after QKV gemm
  float* pks  = (float*)(ws + 8*MB);
  float* kvf  = (float*)(ws + 9*MB);
  float* ksf  = (float*)(ws + 10*MB);
  u16* att    = (u16*)(ws + 104*MB);   // reuses vbuf after kvpart
  u16* proj16 = (u16*)(ws + 40*MB);    // reuses phiq after attn
  float* bcat = out + ((size_t)out_size - 4096);  // d_out tail, dead before expmap

  wconv_k<<<4108, 256, 0, stream>>>(Wq, Wk, Wv, Wo, bq, bk, bv, wbf, bcat);
  logmap_k<<<ROWS, 256, 0, stream>>>(x, cv, xt);
  gemm8_k<<<768, 512, 0, stream>>>(xt, wbf, bcat, phiq,
                                   (size_t)ROWS*Dd, 12, 2);      // fused QKV
  kvpart_k<<<dim3(8,64), 256, 0, stream>>>(phik, vbuf, pkv, pks);
  kvred_k<<<64, 256, 0, stream>>>(pkv, pks, kvf, ksf);
  attn_k<<<dim3(64,64), 256, 0, stream>>>(phiq, kvf, ksf, att);
  gemm8_k<<<256, 512, 0, stream>>>(att, wbf + (size_t)3*(1u<<20), bo, proj16,
                                   0, 4, 0);                     // out-proj
  expmap_k<<<ROWS, 256, 0, stream>>>(proj16, cv, out);
}

// Round 5
// 319.289 us; speedup vs baseline: 1.2314x; 1.0298x over previous
//
#include <hip/hip_runtime.h>
#include <cstdint>
#include <cstddef>

#define Bb 4
#define Nn 4096
#define Dd 1024
#define Hh 16
#define ROWS (Bb*Nn)   // 16384

typedef unsigned short u16;
typedef float    f32x4 __attribute__((ext_vector_type(4)));
typedef _Float16 f16x8 __attribute__((ext_vector_type(8)));
typedef u16      u16x4 __attribute__((ext_vector_type(4)));
typedef u16      u16x8 __attribute__((ext_vector_type(8)));

__device__ inline u16 f2h(float f){ _Float16 h=(_Float16)f; return __builtin_bit_cast(u16,h); }
__device__ inline float h2f(u16 u){ return (float)__builtin_bit_cast(_Float16,u); }

__device__ inline void gl_lds16(const void* g, void* l){
  __builtin_amdgcn_global_load_lds(
      (const __attribute__((address_space(1))) void*)g,
      (__attribute__((address_space(3))) void*)l,
      16, 0, 0);
}

// ------- weights fp32->fp16, plus q/k/v bias concat -------
__global__ __launch_bounds__(256) void wconv_k(const float* __restrict__ wq,
    const float* __restrict__ wk, const float* __restrict__ wv,
    const float* __restrict__ wo,
    const float* __restrict__ bq, const float* __restrict__ bk,
    const float* __restrict__ bv,
    u16* __restrict__ wbf, float* __restrict__ bcat)
{
  const int idx = blockIdx.x*256 + threadIdx.x;
  if (idx < (1<<20)){
    const int which = idx >> 18;
    const int rem = idx & ((1<<18)-1);
    const float* src = which==0?wq:which==1?wk:which==2?wv:wo;
    const f32x4 v = ((const f32x4*)src)[rem];
    u16x4 o;
    #pragma unroll
    for (int i=0;i<4;i++) o[i]=f2h(v[i]);
    ((u16x4*)(wbf + (size_t)which*(1u<<20)))[rem] = o;
  } else {
    const int t = idx - (1<<20);
    if (t < 3072)
      bcat[t] = (t<1024) ? bq[t] : (t<2048) ? bk[t-1024] : bv[t-2048];
  }
}

// ------- log map: x -> x_tan (fp16) -------
__global__ __launch_bounds__(256) void logmap_k(const float* __restrict__ x,
    const float* __restrict__ curv, u16* __restrict__ xt)
{
  const int row = blockIdx.x, tid = threadIdx.x;
  const f32x4 v = ((const f32x4*)(x + (size_t)row*Dd))[tid];
  float ss = v[0]*v[0] + v[1]*v[1] + v[2]*v[2] + v[3]*v[3];
  #pragma unroll
  for (int o=32;o>0;o>>=1) ss += __shfl_down(ss, o, 64);
  __shared__ float red[4];
  if ((tid & 63) == 0) red[tid>>6] = ss;
  __syncthreads();
  const float sum = red[0]+red[1]+red[2]+red[3];
  const float c  = fmaxf(fabsf(curv[0]), 1e-6f);
  const float sc = sqrtf(fmaxf(c, 1e-6f));
  const float xn = fminf(fmaxf(sqrtf(sum), 1e-6f), 0.999f);
  const float a  = sc * xn;
  const float scale = atanhf(a) / (a + 1e-8f);
  u16x4 o;
  #pragma unroll
  for (int i=0;i<4;i++) o[i] = f2h(v[i]*scale);
  ((u16x4*)(xt + (size_t)row*Dd))[tid] = o;
}

// ------- exp map: proj (fp16) -> out (fp32) -------
__global__ __launch_bounds__(256) void expmap_k(const u16* __restrict__ proj,
    const float* __restrict__ curv, float* __restrict__ out)
{
  const int row = blockIdx.x, tid = threadIdx.x;
  const u16x4 hv = ((const u16x4*)(proj + (size_t)row*Dd))[tid];
  float v[4];
  #pragma unroll
  for (int i=0;i<4;i++) v[i]=h2f(hv[i]);
  float ss = v[0]*v[0]+v[1]*v[1]+v[2]*v[2]+v[3]*v[3];
  #pragma unroll
  for (int o=32;o>0;o>>=1) ss += __shfl_down(ss,o,64);
  __shared__ float red[4];
  if ((tid&63)==0) red[tid>>6]=ss;
  __syncthreads();
  const float sum = red[0]+red[1]+red[2]+red[3];
  const float c  = fmaxf(fabsf(curv[0]),1e-6f);
  const float sc = sqrtf(fmaxf(c,1e-6f));
  const float vn = fminf(fmaxf(sqrtf(sum),1e-6f),15.0f);
  const float a  = sc*vn;
  const float scale = tanhf(fminf(a,15.0f))/(a + 1e-8f);
  f32x4 o;
  #pragma unroll
  for (int i=0;i<4;i++) o[i]=v[i]*scale;
  ((f32x4*)(out + (size_t)row*Dd))[tid]=o;
}

// ------- 256x256-tile GEMM: out = A @ W^T + bias (fp16 MFMA), opt phi -------
// 8 waves (2Mx4N), BK=64, dbuf LDS, counted-vmcnt pipeline (T4): stage t+2
// after the read-done barrier, wait vmcnt(8) so t+2's loads stay in flight.
__global__ __launch_bounds__(512, 1) void gemm8_k(
    const u16* __restrict__ A, const u16* __restrict__ W,
    const float* __restrict__ bias,
    u16* __restrict__ outb, size_t mode_stride, int nbn, int phi_modes)
{
  __shared__ __align__(16) char smem[131072];

  const int nwg = gridDim.x;
  const int bid = blockIdx.x;
  const int wgid = (bid & 7)*(nwg >> 3) + (bid >> 3);   // XCD-chunked (nwg%8==0)
  const int bm = wgid / nbn, bn = wgid % nbn;           // bm-major: A-tile L2 reuse
  const int bm0 = bm*256, bn0 = bn*256;

  const int tid = threadIdx.x;
  const int w = tid >> 6, lane = tid & 63;
  const int wr = w >> 2, wc = w & 3;                    // 2M x 4N wave grid
  const int l8 = lane >> 3, l7 = lane & 7;

  f32x4 acc[8][4];
  #pragma unroll
  for (int i=0;i<8;i++)
    #pragma unroll
    for (int j=0;j<4;j++) acc[i][j] = (f32x4)(0.f);

  auto STAGE = [&](int d, int kt){
    char* Ab = smem + d*65536;
    char* Bbp = smem + d*65536 + 32768;
    #pragma unroll
    for (int i=0;i<4;i++){
      const int r = w*32 + i*8 + l8;
      const int cch = l7 ^ (r & 7);
      gl_lds16(A + (size_t)(bm0 + r)*Dd + kt*64 + cch*8, Ab + (w*32+i*8)*128);
      gl_lds16(W + (size_t)(bn0 + r)*Dd + kt*64 + cch*8, Bbp + (w*32+i*8)*128);
    }
  };

  auto COMPUTE = [&](int d){
    const char* Ab = smem + d*65536;
    const char* Bbp = smem + d*65536 + 32768;
    #pragma unroll
    for (int ks=0; ks<2; ks++){
      f16x8 bf[4];
      #pragma unroll
      for (int ni=0; ni<4; ni++){
        const int br = wc*64 + ni*16 + (lane & 15);
        const int cb = (ks*64 + (lane>>4)*16) ^ ((br & 7) << 4);   // T2 swizzle
        bf[ni] = *(const f16x8*)(Bbp + br*128 + cb);
      }
      __builtin_amdgcn_s_setprio(1);
      #pragma unroll
      for (int mi=0; mi<8; mi++){
        const int ar = wr*128 + mi*16 + (lane & 15);
        const int cb = (ks*64 + (lane>>4)*16) ^ ((ar & 7) << 4);
        const f16x8 af = *(const f16x8*)(Ab + ar*128 + cb);
        #pragma unroll
        for (int ni=0; ni<4; ni++)
          acc[mi][ni] = __builtin_amdgcn_mfma_f32_16x16x32_f16(af, bf[ni], acc[mi][ni], 0,0,0);
      }
      __builtin_amdgcn_s_setprio(0);
    }
  };

  // prologue: stage t0,t1; wait t0 only (t1 stays in flight)
  STAGE(0, 0);
  STAGE(1, 1);
  asm volatile("s_waitcnt vmcnt(8)" ::: "memory");
  __builtin_amdgcn_s_barrier();
  __builtin_amdgcn_sched_barrier(0);

  int d = 0;
  for (int kt = 0; kt < Dd/64; ++kt){
    COMPUTE(d);
    __builtin_amdgcn_sched_barrier(0);
    __builtin_amdgcn_s_barrier();            // all waves done reading buf d
    __builtin_amdgcn_sched_barrier(0);
    if (kt < Dd/64 - 2){
      STAGE(d, kt+2);                        // overwrite buf d with tile t+2
      asm volatile("s_waitcnt vmcnt(8)" ::: "memory");  // t+1 landed, t+2 in flight
    } else {
      asm volatile("s_waitcnt vmcnt(0)" ::: "memory");  // tail: drain
    }
    __builtin_amdgcn_s_barrier();            // data-ready
    __builtin_amdgcn_sched_barrier(0);
    d ^= 1;
  }

  // ---- epilogue: bias+phi in-register, LDS transpose (256x256 fp16), coalesced stores
  u16* Ts = (u16*)smem;
  const int dophi = (bn0 >> 10) < phi_modes;
  #pragma unroll
  for (int ni=0;ni<4;ni++){
    const int col = wc*64 + ni*16 + (lane & 15);
    const float bs = bias[bn0 + col];
    #pragma unroll
    for (int mi=0;mi<8;mi++){
      const int row0 = wr*128 + mi*16 + ((lane>>4)<<2);
      #pragma unroll
      for (int r=0;r<4;r++){
        float val = acc[mi][ni][r] + bs;
        if (dophi) val = val > 0.f ? val + 1.f : __expf(val);
        const int row = row0 + r;
        const int bo_ = (row*512 + col*2) ^ ((row&7)<<4);
        *(u16*)((char*)Ts + bo_) = f2h(val);
      }
    }
  }
  __syncthreads();
  {
    #pragma unroll
    for (int j=0;j<16;j++){
      const int row = j*16 + w*2 + (lane>>5);
      const int cb2 = (lane&31)*16;
      const int bo_ = (row*512 + cb2) ^ ((row&7)<<4);
      u16* ob = outb + (size_t)(bn0 >> 10) * mode_stride
                     + (size_t)(bm0 + row)*Dd + (bn0 & 1023) + (cb2>>1);
      *(u16x8*)ob = *(const u16x8*)((const char*)Ts + bo_);
    }
  }
}

// ------- kv partials: kv[f][d] = sum_n phik[n,f]*v[n,d] -------
__global__ __launch_bounds__(256) void kvpart_k(const u16* __restrict__ phik,
    const u16* __restrict__ vbuf, float* __restrict__ pkv, float* __restrict__ pks)
{
  const int nc = blockIdx.x, bh = blockIdx.y;
  const int b = bh>>4, h = bh&15;
  const int tid = threadIdx.x;
  const int f0 = (tid&15)*4, d0 = (tid>>4)*4;
  __shared__ __align__(16) u16 ps[16*64];
  __shared__ __align__(16) u16 vs[16*64];
  float acc[4][4];
  float ks[4];
  #pragma unroll
  for (int i=0;i<4;i++){ ks[i]=0.f;
    #pragma unroll
    for (int j=0;j<4;j++) acc[i][j]=0.f; }
  const size_t base = ((size_t)b*Nn + nc*512)*Dd + h*64;
  const int half = tid>>7, rr = (tid&127)>>3, cc = (tid&7)*8;
  const u16* src = half ? vbuf : phik;
  u16* dst = half ? vs : ps;
  const int wb = rr*128 + ((cc*2) ^ ((rr&7)<<4));   // swizzled LDS write (byte off = cc*2)
  for (int it=0; it<32; ++it){
    __syncthreads();
    *(u16x8*)((char*)dst + wb) = *(const u16x8*)(src + base + (size_t)(it*16+rr)*Dd + cc);
    __syncthreads();
    #pragma unroll 4
    for (int nn=0;nn<16;nn++){
      const u16* pf = (const u16*)((const char*)ps + nn*128 + ((f0*2) ^ ((nn&7)<<4)));
      const u16* vf = (const u16*)((const char*)vs + nn*128 + ((d0*2) ^ ((nn&7)<<4)));
      float pk[4], vv[4];
      #pragma unroll
      for (int i=0;i<4;i++) pk[i]=h2f(pf[i]);
      #pragma unroll
      for (int j=0;j<4;j++) vv[j]=h2f(vf[j]);
      #pragma unroll
      for (int i=0;i<4;i++)
        #pragma unroll
        for (int j=0;j<4;j++) acc[i][j] += pk[i]*vv[j];
      if (tid < 16){
        #pragma unroll
        for (int i=0;i<4;i++) ks[i] += pk[i];
      }
    }
  }
  float* o = pkv + (size_t)(bh*8+nc)*4096;
  #pragma unroll
  for (int i=0;i<4;i++){
    f32x4 t;
    #pragma unroll
    for (int j=0;j<4;j++) t[j]=acc[i][j];
    *(f32x4*)&o[(f0+i)*64 + d0] = t;
  }
  if (tid < 16){
    float* os = pks + (size_t)(bh*8+nc)*64;
    #pragma unroll
    for (int i=0;i<4;i++) os[tid*4+i]=ks[i];
  }
}

// ------- reduce partials; emit transposed, pre-swizzled, hi/lo fp16 kvt -------
// kvt[bh][2][80][64] u16: row d (0..63) col f; row 64 = k_sum; rows 65-79 = 0.
// element (d,f) stored at col f ^ ((d&7)<<3)  (= byte XOR ((d&7)<<4)).
__global__ __launch_bounds__(256) void kvred_k(const float* __restrict__ pkv,
    const float* __restrict__ pks, u16* __restrict__ kvt)
{
  const int bh = blockIdx.x, tid = threadIdx.x;
  u16* basep = kvt + (size_t)bh*10240;
  #pragma unroll
  for (int i=0;i<4;i++){
    const int e = tid*16 + i*4;
    f32x4 s = (f32x4)(0.f);
    for (int p=0;p<8;p++)
      s += *(const f32x4*)&pkv[(size_t)(bh*8+p)*4096 + e];
    const int f = e>>6, dd = e&63;
    #pragma unroll
    for (int j=0;j<4;j++){
      const int r = dd+j;
      const u16 hi = f2h(s[j]);
      const int col = f ^ ((r&7)<<3);
      basep[r*64 + col] = hi;
      basep[5120 + r*64 + col] = f2h(s[j] - h2f(hi));
    }
  }
  if (tid < 64){
    float s=0.f;
    for (int p=0;p<8;p++) s += pks[(size_t)(bh*8+p)*64 + tid];
    const u16 hi = f2h(s);
    basep[64*64 + tid] = hi;                       // (64&7)==0: no swizzle
    basep[5120 + 64*64 + tid] = f2h(s - h2f(hi));
  }
  if (tid < 240){                                  // zero rows 65..79
    const int r = 65 + (tid>>4), c4 = (tid&15)*4;
    *(u16x4*)&basep[r*64 + c4] = (u16x4)(0);
    *(u16x4*)&basep[5120 + r*64 + c4] = (u16x4)(0);
  }
}

// ------- attention core via MFMA: out = (phiq @ kv) / (phiq @ ksum) -------
// 4 waves; wave w owns rows n0+w*16..+15. B = kvt hi/lo (col 64 = normalizer).
__global__ __launch_bounds__(256) void attn2_k(const u16* __restrict__ phiq,
    const u16* __restrict__ kvt, u16* __restrict__ att)
{
  const int bh = blockIdx.y, b = bh>>4, h = bh&15;
  const int n0 = blockIdx.x*64;
  const int tid = threadIdx.x;
  const int w = tid>>6, lane = tid&63;
  __shared__ __align__(16) u16 kvs[10240];   // [2][80][64], pre-swizzled rows
  __shared__ __align__(16) u16 pqs[64*64];   // 64x64 tile, swizzled rows

  {
    const char* src = (const char*)(kvt + (size_t)bh*10240);
    #pragma unroll
    for (int j=0;j<5;j++)
      gl_lds16(src + j*4096 + w*1024 + lane*16, (char*)kvs + j*4096 + w*1024);
    const u16* qsrc = phiq + ((size_t)(b*Nn) + n0)*Dd + h*64;
    const int l8 = lane>>3, l7 = lane&7;
    #pragma unroll
    for (int i=0;i<2;i++){
      const int r = w*16 + i*8 + l8;
      const int cch = l7 ^ (r&7);
      gl_lds16(qsrc + (size_t)r*Dd + cch*8, (char*)pqs + (w*16+i*8)*128);
    }
  }
  __syncthreads();

  f32x4 acc[5];
  #pragma unroll
  for (int ni=0;ni<5;ni++) acc[ni] = (f32x4)(0.f);
  #pragma unroll
  for (int ks=0; ks<2; ks++){
    const int ar = w*16 + (lane&15);
    const int acb = (ks*64 + (lane>>4)*16) ^ ((ar&7)<<4);
    const f16x8 af = *(const f16x8*)((const char*)pqs + ar*128 + acb);
    #pragma unroll
    for (int ni=0; ni<5; ni++){
      const int br = ni*16 + (lane&15);
      const int bcb = (ks*64 + (lane>>4)*16) ^ ((br&7)<<4);
      const f16x8 bh_ = *(const f16x8*)((const char*)kvs + br*128 + bcb);
      const f16x8 bl_ = *(const f16x8*)((const char*)kvs + 10240 + br*128 + bcb);
      acc[ni] = __builtin_amdgcn_mfma_f32_16x16x32_f16(af, bh_, acc[ni], 0,0,0);
      acc[ni] = __builtin_amdgcn_mfma_f32_16x16x32_f16(af, bl_, acc[ni], 0,0,0);
    }
  }

  #pragma unroll
  for (int r=0;r<4;r++){
    const float nrm = __shfl(acc[4][r], (lane & 48), 64);   // col 64 of C
    const float inv = 1.f / fmaxf(nrm, 1e-6f);
    const int row = n0 + w*16 + ((lane>>4)<<2) + r;
    u16* ob = att + ((size_t)(b*Nn) + row)*Dd + h*64 + (lane&15);
    #pragma unroll
    for (int ni=0; ni<4; ni++)
      ob[ni*16] = f2h(acc[ni][r] * inv);
  }
}

extern "C" void kernel_launch(void* const* d_in, const int* in_sizes, int n_in,
                              void* d_out, int out_size, void* d_ws, size_t ws_size,
                              hipStream_t stream)
{
  const float* x  = (const float*)d_in[0];
  const float* cv = (const float*)d_in[1];
  const float* Wq = (const float*)d_in[2];
  const float* bq = (const float*)d_in[3];
  const float* Wk = (const float*)d_in[4];
  const float* bk = (const float*)d_in[5];
  const float* Wv = (const float*)d_in[6];
  const float* bv = (const float*)d_in[7];
  const float* Wo = (const float*)d_in[8];
  const float* bo = (const float*)d_in[9];
  float* out = (float*)d_out;
  char* ws = (char*)d_ws;
  const size_t MB = 1u<<20;
  if (ws_size < 136*MB) return;

  u16* xt     = (u16*)(ws + 0);        // 32 MiB, dead after QKV gemm
  u16* wbf    = (u16*)(ws + 32*MB);    // 8 MiB (Wq|Wk|Wv|Wo fp16)
  u16* phiq   = (u16*)(ws + 40*MB);    // 32 MiB (phiq|phik|vbuf contiguous)
  u16* phik   = (u16*)(ws + 72*MB);
  u16* vbuf   = (u16*)(ws + 104*MB);
  float* pkv  = (float*)(ws + 0);      // reuses xt region after QKV gemm
  float* pks  = (float*)(ws + 8*MB);
  u16* kvt    = (u16*)(ws + 9*MB);     // 1.25 MiB [64][2][80][64] u16
  u16* att    = (u16*)(ws + 104*MB);   // reuses vbuf after kvpart
  u16* proj16 = (u16*)(ws + 40*MB);    // reuses phiq after attn
  float* bcat = out + ((size_t)out_size - 4096);  // d_out tail, dead before expmap

  wconv_k<<<4108, 256, 0, stream>>>(Wq, Wk, Wv, Wo, bq, bk, bv, wbf, bcat);
  logmap_k<<<ROWS, 256, 0, stream>>>(x, cv, xt);
  gemm8_k<<<768, 512, 0, stream>>>(xt, wbf, bcat, phiq,
                                   (size_t)ROWS*Dd, 12, 2);      // fused QKV
  kvpart_k<<<dim3(8,64), 256, 0, stream>>>(phik, vbuf, pkv, pks);
  kvred_k<<<64, 256, 0, stream>>>(pkv, pks, kvt);
  attn2_k<<<dim3(64,64), 256, 0, stream>>>(phiq, kvt, att);
  gemm8_k<<<256, 512, 0, stream>>>(att, wbf + (size_t)3*(1u<<20), bo, proj16,
                                   0, 4, 0);                     // out-proj
  expmap_k<<<ROWS, 256, 0, stream>>>(proj16, cv, out);
}

// Round 6
// 311.058 us; speedup vs baseline: 1.2640x; 1.0265x over previous
//
#include <hip/hip_runtime.h>
#include <cstdint>
#include <cstddef>

#define Bb 4
#define Nn 4096
#define Dd 1024
#define Hh 16
#define ROWS (Bb*Nn)   // 16384

typedef unsigned short u16;
typedef float    f32x4 __attribute__((ext_vector_type(4)));
typedef _Float16 f16x8 __attribute__((ext_vector_type(8)));
typedef u16      u16x4 __attribute__((ext_vector_type(4)));
typedef u16      u16x8 __attribute__((ext_vector_type(8)));

__device__ inline u16 f2h(float f){ _Float16 h=(_Float16)f; return __builtin_bit_cast(u16,h); }
__device__ inline float h2f(u16 u){ return (float)__builtin_bit_cast(_Float16,u); }

__device__ inline void gl_lds16(const void* g, void* l){
  __builtin_amdgcn_global_load_lds(
      (const __attribute__((address_space(1))) void*)g,
      (__attribute__((address_space(3))) void*)l,
      16, 0, 0);
}

// ------- weights fp32->fp16, plus q/k/v bias concat -------
__global__ __launch_bounds__(256) void wconv_k(const float* __restrict__ wq,
    const float* __restrict__ wk, const float* __restrict__ wv,
    const float* __restrict__ wo,
    const float* __restrict__ bq, const float* __restrict__ bk,
    const float* __restrict__ bv,
    u16* __restrict__ wbf, float* __restrict__ bcat)
{
  const int idx = blockIdx.x*256 + threadIdx.x;
  if (idx < (1<<20)){
    const int which = idx >> 18;
    const int rem = idx & ((1<<18)-1);
    const float* src = which==0?wq:which==1?wk:which==2?wv:wo;
    const f32x4 v = ((const f32x4*)src)[rem];
    u16x4 o;
    #pragma unroll
    for (int i=0;i<4;i++) o[i]=f2h(v[i]);
    ((u16x4*)(wbf + (size_t)which*(1u<<20)))[rem] = o;
  } else {
    const int t = idx - (1<<20);
    if (t < 3072)
      bcat[t] = (t<1024) ? bq[t] : (t<2048) ? bk[t-1024] : bv[t-2048];
  }
}

// ------- log map: x -> x_tan (fp16) -------
__global__ __launch_bounds__(256) void logmap_k(const float* __restrict__ x,
    const float* __restrict__ curv, u16* __restrict__ xt)
{
  const int row = blockIdx.x, tid = threadIdx.x;
  const f32x4 v = ((const f32x4*)(x + (size_t)row*Dd))[tid];
  float ss = v[0]*v[0] + v[1]*v[1] + v[2]*v[2] + v[3]*v[3];
  #pragma unroll
  for (int o=32;o>0;o>>=1) ss += __shfl_down(ss, o, 64);
  __shared__ float red[4];
  if ((tid & 63) == 0) red[tid>>6] = ss;
  __syncthreads();
  const float sum = red[0]+red[1]+red[2]+red[3];
  const float c  = fmaxf(fabsf(curv[0]), 1e-6f);
  const float sc = sqrtf(fmaxf(c, 1e-6f));
  const float xn = fminf(fmaxf(sqrtf(sum), 1e-6f), 0.999f);
  const float a  = sc * xn;
  const float scale = atanhf(a) / (a + 1e-8f);
  u16x4 o;
  #pragma unroll
  for (int i=0;i<4;i++) o[i] = f2h(v[i]*scale);
  ((u16x4*)(xt + (size_t)row*Dd))[tid] = o;
}

// ------- exp map: proj (fp16) -> out (fp32) -------
__global__ __launch_bounds__(256) void expmap_k(const u16* __restrict__ proj,
    const float* __restrict__ curv, float* __restrict__ out)
{
  const int row = blockIdx.x, tid = threadIdx.x;
  const u16x4 hv = ((const u16x4*)(proj + (size_t)row*Dd))[tid];
  float v[4];
  #pragma unroll
  for (int i=0;i<4;i++) v[i]=h2f(hv[i]);
  float ss = v[0]*v[0]+v[1]*v[1]+v[2]*v[2]+v[3]*v[3];
  #pragma unroll
  for (int o=32;o>0;o>>=1) ss += __shfl_down(ss,o,64);
  __shared__ float red[4];
  if ((tid&63)==0) red[tid>>6]=ss;
  __syncthreads();
  const float sum = red[0]+red[1]+red[2]+red[3];
  const float c  = fmaxf(fabsf(curv[0]),1e-6f);
  const float sc = sqrtf(fmaxf(c,1e-6f));
  const float vn = fminf(fmaxf(sqrtf(sum),1e-6f),15.0f);
  const float a  = sc*vn;
  const float scale = tanhf(fminf(a,15.0f))/(a + 1e-8f);
  f32x4 o;
  #pragma unroll
  for (int i=0;i<4;i++) o[i]=v[i]*scale;
  ((f32x4*)(out + (size_t)row*Dd))[tid]=o;
}

// ------- 256x256-tile GEMM, 8-phase schedule (m201 template port) -------
// 8 waves (2Mx4N), BK=64, 2x64KB dbuf, half-tile (16KB) staging granularity.
// Per 2-K-tile iteration: 8 phases; stages P0/P1:buf1.A<-t(2i+1),
// P2/P3:buf0.B<-t(2i+2), P4/P5:buf0.A<-t(2i+2), P6/P7:buf1.B<-t(2i+3).
// vmcnt(4) at P3/P7 (counted, never 0 mid-loop); lgkmcnt(0)+sched_barrier
// per phase (rule 18). B-frags register-cached per K-tile (freed at quad 0).
__global__ __launch_bounds__(512, 1) void gemm8p_k(
    const u16* __restrict__ A, const u16* __restrict__ W,
    const float* __restrict__ bias,
    u16* __restrict__ outb, size_t mode_stride, int nbn, int phi_modes)
{
  __shared__ __align__(16) char smem[131072];

  const int nwg = gridDim.x;
  const int bid = blockIdx.x;
  const int wgid = (bid & 7)*(nwg >> 3) + (bid >> 3);   // XCD-chunked (nwg%8==0)
  const int bm = wgid / nbn, bn = wgid % nbn;           // bm-major: A-tile L2 reuse
  const int bm0 = bm*256, bn0 = bn*256;

  const int tid = threadIdx.x;
  const int w = tid >> 6, lane = tid & 63;
  const int wr = w >> 2, wc = w & 3;                    // 2M x 4N wave grid

  f32x4 acc[8][4];
  #pragma unroll
  for (int i=0;i<8;i++)
    #pragma unroll
    for (int j=0;j<4;j++) acc[i][j] = (f32x4)(0.f);
  f16x8 bfc[2][4];                                      // B-frags, cached per K-tile

  // stage one 16KB half: dbuf d, matrix mat (0=A,1=B), half h, K-tile kt.
  // LDS linear dest (wave-uniform + lane*16), pre-swizzled global source.
  auto STG = [&](int d, int mat, int h, int kt){
    char* base = smem + d*65536 + mat*32768 + h*16384;
    const u16* srcb = mat ? (W + (size_t)bn0*Dd) : (A + (size_t)bm0*Dd);
    #pragma unroll
    for (int j=0;j<2;j++){
      const int cj = w*128 + j*64 + lane;     // chunk id 0..1023
      const int r = cj>>3, ch = cj&7;
      const int cch = ch ^ (r&7);
      gl_lds16(srcb + (size_t)(h*128 + r)*Dd + kt*64 + cch*8, base + cj*16);
    }
  };

  // prologue: tile0 -> buf0 (A+B), tile1 -> buf1.B. buf1.A staged at it0 P0/P1.
  STG(0,0,0,0); STG(0,0,1,0); STG(0,1,0,0); STG(0,1,1,0);
  STG(1,1,0,1); STG(1,1,1,1);
  asm volatile("s_waitcnt vmcnt(4)" ::: "memory");      // buf0's 8 landed
  __builtin_amdgcn_s_barrier();
  __builtin_amdgcn_sched_barrier(0);

  #pragma unroll 1
  for (int it=0; it<8; ++it){
    const int te = 2*it;
    #pragma unroll
    for (int ph=0; ph<8; ++ph){
      const int d = ph>>2, p4 = ph&3;
      const char* Ab = smem + d*65536;
      const char* Bbp = smem + d*65536 + 32768;
      // ---- ds-reads for THIS phase's MFMA ----
      if (p4 == 0){
        #pragma unroll
        for (int ks=0;ks<2;ks++)
          #pragma unroll
          for (int ni=0;ni<4;ni++){
            const int br = wc*64 + ni*16 + (lane&15);
            const int cb = (ks*64 + ((lane>>4)<<4)) ^ ((br&7)<<4);
            bfc[ks][ni] = *(const f16x8*)(Bbp + br*128 + cb);
          }
      }
      f16x8 af[2][2];
      #pragma unroll
      for (int dm=0;dm<2;dm++)
        #pragma unroll
        for (int ks=0;ks<2;ks++){
          const int ar = wr*128 + (p4*2+dm)*16 + (lane&15);
          const int cb = (ks*64 + ((lane>>4)<<4)) ^ ((ar&7)<<4);
          af[dm][ks] = *(const f16x8*)(Ab + ar*128 + cb);
        }
      // ---- stage one half-tile (targets freed regions only) ----
      if (ph == 0) STG(1,0,0, te+1);
      else if (ph == 1) STG(1,0,1, te+1);
      else if (it < 7){
        if      (ph == 2) STG(0,1,0, te+2);
        else if (ph == 3) STG(0,1,1, te+2);
        else if (ph == 4) STG(0,0,0, te+2);
        else if (ph == 5) STG(0,0,1, te+2);
        else if (ph == 6) STG(1,1,0, te+3);
        else              STG(1,1,1, te+3);
      }
      __builtin_amdgcn_s_barrier();
      asm volatile("s_waitcnt lgkmcnt(0)" ::: "memory");
      __builtin_amdgcn_sched_barrier(0);                 // rule 18
      __builtin_amdgcn_s_setprio(1);
      #pragma unroll
      for (int ks=0;ks<2;ks++)
        #pragma unroll
        for (int dm=0;dm<2;dm++)
          #pragma unroll
          for (int ni=0;ni<4;ni++)
            acc[p4*2+dm][ni] = __builtin_amdgcn_mfma_f32_16x16x32_f16(
                af[dm][ks], bfc[ks][ni], acc[p4*2+dm][ni], 0,0,0);
      __builtin_amdgcn_s_setprio(0);
      if (ph == 3){
        if (it < 7) asm volatile("s_waitcnt vmcnt(4)" ::: "memory");
        else        asm volatile("s_waitcnt vmcnt(0)" ::: "memory");
      } else if (ph == 7 && it < 7){
        asm volatile("s_waitcnt vmcnt(4)" ::: "memory");
      }
      __builtin_amdgcn_s_barrier();
      __builtin_amdgcn_sched_barrier(0);
    }
  }

  // ---- epilogue: bias+phi in-register, LDS transpose (256x512B), coalesced stores
  u16* Ts = (u16*)smem;
  const int dophi = (bn0 >> 10) < phi_modes;
  #pragma unroll
  for (int ni=0;ni<4;ni++){
    const int col = wc*64 + ni*16 + (lane & 15);
    const float bs = bias[bn0 + col];
    #pragma unroll
    for (int mi=0;mi<8;mi++){
      const int row0 = wr*128 + mi*16 + ((lane>>4)<<2);
      #pragma unroll
      for (int r=0;r<4;r++){
        float val = acc[mi][ni][r] + bs;
        if (dophi) val = val > 0.f ? val + 1.f : __expf(val);
        const int row = row0 + r;
        const int bo_ = (row*512 + col*2) ^ ((row&7)<<4);
        *(u16*)((char*)Ts + bo_) = f2h(val);
      }
    }
  }
  __syncthreads();
  {
    #pragma unroll
    for (int j=0;j<16;j++){
      const int row = j*16 + w*2 + (lane>>5);
      const int cb2 = (lane&31)*16;
      const int bo_ = (row*512 + cb2) ^ ((row&7)<<4);
      u16* ob = outb + (size_t)(bn0 >> 10) * mode_stride
                     + (size_t)(bm0 + row)*Dd + (bn0 & 1023) + (cb2>>1);
      *(u16x8*)ob = *(const u16x8*)((const char*)Ts + bo_);
    }
  }
}

// ------- kv partials: kv[f][d] = sum_n phik[n,f]*v[n,d] -------
__global__ __launch_bounds__(256) void kvpart_k(const u16* __restrict__ phik,
    const u16* __restrict__ vbuf, float* __restrict__ pkv, float* __restrict__ pks)
{
  const int nc = blockIdx.x, bh = blockIdx.y;
  const int b = bh>>4, h = bh&15;
  const int tid = threadIdx.x;
  const int f0 = (tid&15)*4, d0 = (tid>>4)*4;
  __shared__ __align__(16) u16 ps[16*64];
  __shared__ __align__(16) u16 vs[16*64];
  float acc[4][4];
  float ks[4];
  #pragma unroll
  for (int i=0;i<4;i++){ ks[i]=0.f;
    #pragma unroll
    for (int j=0;j<4;j++) acc[i][j]=0.f; }
  const size_t base = ((size_t)b*Nn + nc*512)*Dd + h*64;
  const int half = tid>>7, rr = (tid&127)>>3, cc = (tid&7)*8;
  const u16* src = half ? vbuf : phik;
  u16* dst = half ? vs : ps;
  const int wb = rr*128 + ((cc*2) ^ ((rr&7)<<4));   // swizzled LDS write (byte off = cc*2)
  for (int it=0; it<32; ++it){
    __syncthreads();
    *(u16x8*)((char*)dst + wb) = *(const u16x8*)(src + base + (size_t)(it*16+rr)*Dd + cc);
    __syncthreads();
    #pragma unroll 4
    for (int nn=0;nn<16;nn++){
      const u16* pf = (const u16*)((const char*)ps + nn*128 + ((f0*2) ^ ((nn&7)<<4)));
      const u16* vf = (const u16*)((const char*)vs + nn*128 + ((d0*2) ^ ((nn&7)<<4)));
      float pk[4], vv[4];
      #pragma unroll
      for (int i=0;i<4;i++) pk[i]=h2f(pf[i]);
      #pragma unroll
      for (int j=0;j<4;j++) vv[j]=h2f(vf[j]);
      #pragma unroll
      for (int i=0;i<4;i++)
        #pragma unroll
        for (int j=0;j<4;j++) acc[i][j] += pk[i]*vv[j];
      if (tid < 16){
        #pragma unroll
        for (int i=0;i<4;i++) ks[i] += pk[i];
      }
    }
  }
  float* o = pkv + (size_t)(bh*8+nc)*4096;
  #pragma unroll
  for (int i=0;i<4;i++){
    f32x4 t;
    #pragma unroll
    for (int j=0;j<4;j++) t[j]=acc[i][j];
    *(f32x4*)&o[(f0+i)*64 + d0] = t;
  }
  if (tid < 16){
    float* os = pks + (size_t)(bh*8+nc)*64;
    #pragma unroll
    for (int i=0;i<4;i++) os[tid*4+i]=ks[i];
  }
}

// ------- reduce partials; emit transposed, pre-swizzled, hi/lo fp16 kvt -------
// kvt[bh][2][80][64] u16: row d (0..63) col f; row 64 = k_sum; rows 65-79 = 0.
// element (d,f) stored at col f ^ ((d&7)<<3)  (= byte XOR ((d&7)<<4)).
__global__ __launch_bounds__(256) void kvred_k(const float* __restrict__ pkv,
    const float* __restrict__ pks, u16* __restrict__ kvt)
{
  const int bh = blockIdx.x, tid = threadIdx.x;
  u16* basep = kvt + (size_t)bh*10240;
  #pragma unroll
  for (int i=0;i<4;i++){
    const int e = tid*16 + i*4;
    f32x4 s = (f32x4)(0.f);
    for (int p=0;p<8;p++)
      s += *(const f32x4*)&pkv[(size_t)(bh*8+p)*4096 + e];
    const int f = e>>6, dd = e&63;
    #pragma unroll
    for (int j=0;j<4;j++){
      const int r = dd+j;
      const u16 hi = f2h(s[j]);
      const int col = f ^ ((r&7)<<3);
      basep[r*64 + col] = hi;
      basep[5120 + r*64 + col] = f2h(s[j] - h2f(hi));
    }
  }
  if (tid < 64){
    float s=0.f;
    for (int p=0;p<8;p++) s += pks[(size_t)(bh*8+p)*64 + tid];
    const u16 hi = f2h(s);
    basep[64*64 + tid] = hi;                       // (64&7)==0: no swizzle
    basep[5120 + 64*64 + tid] = f2h(s - h2f(hi));
  }
  if (tid < 240){                                  // zero rows 65..79
    const int r = 65 + (tid>>4), c4 = (tid&15)*4;
    *(u16x4*)&basep[r*64 + c4] = (u16x4)(0);
    *(u16x4*)&basep[5120 + r*64 + c4] = (u16x4)(0);
  }
}

// ------- attention core via MFMA: out = (phiq @ kv) / (phiq @ ksum) -------
// 4 waves; wave w owns rows n0+w*16..+15. B = kvt hi/lo (col 64 = normalizer).
__global__ __launch_bounds__(256) void attn2_k(const u16* __restrict__ phiq,
    const u16* __restrict__ kvt, u16* __restrict__ att)
{
  const int bh = blockIdx.y, b = bh>>4, h = bh&15;
  const int n0 = blockIdx.x*64;
  const int tid = threadIdx.x;
  const int w = tid>>6, lane = tid&63;
  __shared__ __align__(16) u16 kvs[10240];   // [2][80][64], pre-swizzled rows
  __shared__ __align__(16) u16 pqs[64*64];   // 64x64 tile, swizzled rows

  {
    const char* src = (const char*)(kvt + (size_t)bh*10240);
    #pragma unroll
    for (int j=0;j<5;j++)
      gl_lds16(src + j*4096 + w*1024 + lane*16, (char*)kvs + j*4096 + w*1024);
    const u16* qsrc = phiq + ((size_t)(b*Nn) + n0)*Dd + h*64;
    const int l8 = lane>>3, l7 = lane&7;
    #pragma unroll
    for (int i=0;i<2;i++){
      const int r = w*16 + i*8 + l8;
      const int cch = l7 ^ (r&7);
      gl_lds16(qsrc + (size_t)r*Dd + cch*8, (char*)pqs + (w*16+i*8)*128);
    }
  }
  __syncthreads();

  f32x4 acc[5];
  #pragma unroll
  for (int ni=0;ni<5;ni++) acc[ni] = (f32x4)(0.f);
  #pragma unroll
  for (int ks=0; ks<2; ks++){
    const int ar = w*16 + (lane&15);
    const int acb = (ks*64 + (lane>>4)*16) ^ ((ar&7)<<4);
    const f16x8 af = *(const f16x8*)((const char*)pqs + ar*128 + acb);
    #pragma unroll
    for (int ni=0; ni<5; ni++){
      const int br = ni*16 + (lane&15);
      const int bcb = (ks*64 + (lane>>4)*16) ^ ((br&7)<<4);
      const f16x8 bh_ = *(const f16x8*)((const char*)kvs + br*128 + bcb);
      const f16x8 bl_ = *(const f16x8*)((const char*)kvs + 10240 + br*128 + bcb);
      acc[ni] = __builtin_amdgcn_mfma_f32_16x16x32_f16(af, bh_, acc[ni], 0,0,0);
      acc[ni] = __builtin_amdgcn_mfma_f32_16x16x32_f16(af, bl_, acc[ni], 0,0,0);
    }
  }

  #pragma unroll
  for (int r=0;r<4;r++){
    const float nrm = __shfl(acc[4][r], (lane & 48), 64);   // col 64 of C
    const float inv = 1.f / fmaxf(nrm, 1e-6f);
    const int row = n0 + w*16 + ((lane>>4)<<2) + r;
    u16* ob = att + ((size_t)(b*Nn) + row)*Dd + h*64 + (lane&15);
    #pragma unroll
    for (int ni=0; ni<4; ni++)
      ob[ni*16] = f2h(acc[ni][r] * inv);
  }
}

extern "C" void kernel_launch(void* const* d_in, const int* in_sizes, int n_in,
                              void* d_out, int out_size, void* d_ws, size_t ws_size,
                              hipStream_t stream)
{
  const float* x  = (const float*)d_in[0];
  const float* cv = (const float*)d_in[1];
  const float* Wq = (const float*)d_in[2];
  const float* bq = (const float*)d_in[3];
  const float* Wk = (const float*)d_in[4];
  const float* bk = (const float*)d_in[5];
  const float* Wv = (const float*)d_in[6];
  const float* bv = (const float*)d_in[7];
  const float* Wo = (const float*)d_in[8];
  const float* bo = (const float*)d_in[9];
  float* out = (float*)d_out;
  char* ws = (char*)d_ws;
  const size_t MB = 1u<<20;
  if (ws_size < 136*MB) return;

  u16* xt     = (u16*)(ws + 0);        // 32 MiB, dead after QKV gemm
  u16* wbf    = (u16*)(ws + 32*MB);    // 8 MiB (Wq|Wk|Wv|Wo fp16)
  u16* phiq   = (u16*)(ws + 40*MB);    // 32 MiB (phiq|phik|vbuf contiguous)
  u16* phik   = (u16*)(ws + 72*MB);
  u16* vbuf   = (u16*)(ws + 104*MB);
  float* pkv  = (float*)(ws + 0);      // reuses xt region after QKV gemm
  float* pks  = (float*)(ws + 8*MB);
  u16* kvt    = (u16*)(ws + 9*MB);     // 1.25 MiB [64][2][80][64] u16
  u16* att    = (u16*)(ws + 104*MB);   // reuses vbuf after kvpart
  u16* proj16 = (u16*)(ws + 40*MB);    // reuses phiq after attn
  float* bcat = out + ((size_t)out_size - 4096);  // d_out tail, dead before expmap

  wconv_k<<<4108, 256, 0, stream>>>(Wq, Wk, Wv, Wo, bq, bk, bv, wbf, bcat);
  logmap_k<<<ROWS, 256, 0, stream>>>(x, cv, xt);
  gemm8p_k<<<768, 512, 0, stream>>>(xt, wbf, bcat, phiq,
                                    (size_t)ROWS*Dd, 12, 2);     // fused QKV
  kvpart_k<<<dim3(8,64), 256, 0, stream>>>(phik, vbuf, pkv, pks);
  kvred_k<<<64, 256, 0, stream>>>(pkv, pks, kvt);
  attn2_k<<<dim3(64,64), 256, 0, stream>>>(phiq, kvt, att);
  gemm8p_k<<<256, 512, 0, stream>>>(att, wbf + (size_t)3*(1u<<20), bo, proj16,
                                    0, 4, 0);                    // out-proj
  expmap_k<<<ROWS, 256, 0, stream>>>(proj16, cv, out);
}